// Round 4
// baseline (134.590 us; speedup 1.0000x reference)
//
#include <hip/hip_runtime.h>
#include <math.h>

// Problem constants (fixed by setup_inputs)
#define NP 8192      // pred vertices
#define NG 12000     // gt vertices
#define NFP 16384    // pred faces
#define NFG 24000    // gt faces
#define EPSF 1e-6f

// cdist decomposition
#define ROW_GROUPS 4     // 4 x 2048 pred points
#define ROW_CHUNKS 128
#define ROW_CH 94        // 128*94 = 12032 >= 12000 (padded)
#define ROW_BLOCKS (ROW_GROUPS*ROW_CHUNKS)    // 512
#define COL_GROUPS 6     // 6 x 2048 = 12288 >= 12000
#define COL_CHUNKS 86
#define COL_CH 96        // 86*96 = 8256 >= 8192 (padded)
#define COL_BLOCKS (COL_GROUPS*COL_CHUNKS)    // 516
#define CD_BLOCKS (ROW_BLOCKS + COL_BLOCKS)   // 1028
#define FACE_BLOCKS ((NFG + NFP + 255) / 256) // 158
#define NGPAD (COL_GROUPS*2048)               // 12288

// ---- workspace layout (bytes) ----
static constexpr size_t OFF_ROWPART = 0;          // [128][8192] u64 (d2bits<<32)|idx
static constexpr size_t OFF_COLPART = 8388608;    // [86][12288] f32 d2
static constexpr size_t OFF_GTN     = 12615680;   // NG*3 f32  gt normal accum (raw)
static constexpr size_t OFF_PNN     = 12759680;   // NP*3 f32  pred normal accum
static constexpr size_t OFF_NSUM    = 12857984;   // NP*3 f32  laplacian neighbor sum
static constexpr size_t OFF_DEG     = 12956288;   // NP   f32  laplacian degree
static constexpr size_t OFF_SCAL    = 12989056;   // 8 f32 [sum_row,sum_col,pc,SX,SY,sse,lap,ticket]
#define N_ZERO 93352   // floats from OFF_GTN..end(scal) — accumulators + scal + ticket

__global__ __launch_bounds__(256) void init_kernel(float* __restrict__ zero) {
    int i = blockIdx.x * 256 + threadIdx.x;
    if (i < N_ZERO) zero[i] = 0.0f;
}

// Fused cdist + face-scatter dispatch.
// Blocks [0, ROW_BLOCKS)      : per-pred min+argmin over one 94-pt gt chunk -> rowpart
// Blocks [ROW_BLOCKS, CD)     : per-gt min over one 96-pt pred chunk        -> colpart
// Blocks [CD, CD+FACE_BLOCKS) : face-normal / laplacian scatter (atomics)
// cdist trick: d2 = |p|^2 + (|q|^2 - 2 p.q); (q,|q|^2) staged in LDS -> 3 FMA/eval.
// 8-way register blocking: one ds_read_b128 feeds 8 points (ILP hides latency).
// max(.,0) applied after the min is valid (monotone, |p|^2 const per point).
__global__ __launch_bounds__(256) void mega_kernel(const float* __restrict__ pred,
                                                   const int* __restrict__ pf,
                                                   const float* __restrict__ gt,
                                                   const int* __restrict__ gf,
                                                   unsigned long long* __restrict__ rowpart,
                                                   float* __restrict__ colpart,
                                                   float* __restrict__ gtn,
                                                   float* __restrict__ pnn,
                                                   float* __restrict__ nsum,
                                                   float* __restrict__ deg) {
    __shared__ float4 s[COL_CH];   // 96 >= 94
    int b = blockIdx.x;
    if (b < ROW_BLOCKS) {
        int group = b >> 7;            // 0..3
        int chunk = b & 127;           // 0..127
        int gbase = chunk * ROW_CH;
        int pv0 = group * 2048 + threadIdx.x;
        // own points first (overlap global latency with staging)
        float cx[8], cy[8], cz[8], a2[8], best[8];
        int bi[8];
        #pragma unroll
        for (int k = 0; k < 8; ++k) {
            int pv = pv0 + 256*k;
            float x = pred[3*pv], y = pred[3*pv+1], z = pred[3*pv+2];
            a2[k] = fmaf(x,x, fmaf(y,y, z*z));
            cx[k] = -2.0f*x; cy[k] = -2.0f*y; cz[k] = -2.0f*z;
            best[k] = 3.0e38f; bi[k] = 0;
        }
        for (int j = threadIdx.x; j < ROW_CH; j += 256) {
            int gj = gbase + j;
            if (gj < NG) {
                float x = gt[3*gj], y = gt[3*gj+1], z = gt[3*gj+2];
                s[j] = make_float4(x, y, z, fmaf(x,x, fmaf(y,y, z*z)));
            } else {
                s[j] = make_float4(0.f, 0.f, 0.f, 3.0e38f);
            }
        }
        __syncthreads();
        #pragma unroll 2
        for (int j = 0; j < ROW_CH; ++j) {
            float4 q = s[j];
            #pragma unroll
            for (int k = 0; k < 8; ++k) {
                float t = fmaf(cx[k], q.x, fmaf(cy[k], q.y, fmaf(cz[k], q.z, q.w)));
                if (t < best[k]) { best[k] = t; bi[k] = j; }  // strict < keeps first idx
            }
        }
        #pragma unroll
        for (int k = 0; k < 8; ++k) {
            float d2 = fmaxf(a2[k] + best[k], 0.0f);
            rowpart[(size_t)chunk * NP + pv0 + 256*k] =
                ((unsigned long long)__float_as_uint(d2) << 32) | (unsigned)(gbase + bi[k]);
        }
    } else if (b < CD_BLOCKS) {
        int bb = b - ROW_BLOCKS;
        int group = bb / COL_CHUNKS;   // 0..5
        int chunk = bb % COL_CHUNKS;   // 0..85
        int pbase = chunk * COL_CH;
        int gv0 = group * 2048 + threadIdx.x;
        float cx[8], cy[8], cz[8], a2[8], best[8];
        #pragma unroll
        for (int k = 0; k < 8; ++k) {
            int gv = gv0 + 256*k;
            float x = 0.f, y = 0.f, z = 0.f;
            if (gv < NG) { x = gt[3*gv]; y = gt[3*gv+1]; z = gt[3*gv+2]; }
            a2[k] = fmaf(x,x, fmaf(y,y, z*z));
            cx[k] = -2.0f*x; cy[k] = -2.0f*y; cz[k] = -2.0f*z;
            best[k] = 3.0e38f;
        }
        for (int j = threadIdx.x; j < COL_CH; j += 256) {
            int pj = pbase + j;
            if (pj < NP) {
                float x = pred[3*pj], y = pred[3*pj+1], z = pred[3*pj+2];
                s[j] = make_float4(x, y, z, fmaf(x,x, fmaf(y,y, z*z)));
            } else {
                s[j] = make_float4(0.f, 0.f, 0.f, 3.0e38f);
            }
        }
        __syncthreads();
        #pragma unroll 2
        for (int j = 0; j < COL_CH; ++j) {
            float4 q = s[j];
            #pragma unroll
            for (int k = 0; k < 8; ++k) {
                float t = fmaf(cx[k], q.x, fmaf(cy[k], q.y, fmaf(cz[k], q.z, q.w)));
                best[k] = fminf(best[k], t);
            }
        }
        #pragma unroll
        for (int k = 0; k < 8; ++k) {
            float d2 = fmaxf(a2[k] + best[k], 0.0f);
            colpart[(size_t)chunk * NGPAD + gv0 + 256*k] = d2;  // pads stored, ignored later
        }
    } else {
        // face scatter: gt faces then pred faces
        int t = (b - CD_BLOCKS) * 256 + threadIdx.x;
        if (t < NFG) {
            int i0 = gf[3*t], i1 = gf[3*t+1], i2 = gf[3*t+2];
            float ax = gt[3*i0], ay = gt[3*i0+1], az = gt[3*i0+2];
            float bx = gt[3*i1], by = gt[3*i1+1], bz = gt[3*i1+2];
            float cx = gt[3*i2], cy = gt[3*i2+1], cz = gt[3*i2+2];
            float ux = bx-ax, uy = by-ay, uz = bz-az;
            float wx = cx-ax, wy = cy-ay, wz = cz-az;
            float nx = uy*wz - uz*wy, ny = uz*wx - ux*wz, nz = ux*wy - uy*wx;
            atomicAdd(&gtn[3*i0+0], nx); atomicAdd(&gtn[3*i0+1], ny); atomicAdd(&gtn[3*i0+2], nz);
            atomicAdd(&gtn[3*i1+0], nx); atomicAdd(&gtn[3*i1+1], ny); atomicAdd(&gtn[3*i1+2], nz);
            atomicAdd(&gtn[3*i2+0], nx); atomicAdd(&gtn[3*i2+1], ny); atomicAdd(&gtn[3*i2+2], nz);
        } else if (t < NFG + NFP) {
            int u = t - NFG;
            int i0 = pf[3*u], i1 = pf[3*u+1], i2 = pf[3*u+2];
            float ax = pred[3*i0], ay = pred[3*i0+1], az = pred[3*i0+2];
            float bx = pred[3*i1], by = pred[3*i1+1], bz = pred[3*i1+2];
            float cx = pred[3*i2], cy = pred[3*i2+1], cz = pred[3*i2+2];
            float ux = bx-ax, uy = by-ay, uz = bz-az;
            float wx = cx-ax, wy = cy-ay, wz = cz-az;
            float nx = uy*wz - uz*wy, ny = uz*wx - ux*wz, nz = ux*wy - uy*wx;
            atomicAdd(&pnn[3*i0+0], nx); atomicAdd(&pnn[3*i0+1], ny); atomicAdd(&pnn[3*i0+2], nz);
            atomicAdd(&pnn[3*i1+0], nx); atomicAdd(&pnn[3*i1+1], ny); atomicAdd(&pnn[3*i1+2], nz);
            atomicAdd(&pnn[3*i2+0], nx); atomicAdd(&pnn[3*i2+1], ny); atomicAdd(&pnn[3*i2+2], nz);
            atomicAdd(&nsum[3*i0+0], bx+cx); atomicAdd(&nsum[3*i0+1], by+cy); atomicAdd(&nsum[3*i0+2], bz+cz);
            atomicAdd(&nsum[3*i1+0], cx+ax); atomicAdd(&nsum[3*i1+1], cy+ay); atomicAdd(&nsum[3*i1+2], cz+az);
            atomicAdd(&nsum[3*i2+0], ax+bx); atomicAdd(&nsum[3*i2+1], ay+by); atomicAdd(&nsum[3*i2+2], az+bz);
            atomicAdd(&deg[i0], 2.0f); atomicAdd(&deg[i1], 2.0f); atomicAdd(&deg[i2], 2.0f);
        }
    }
}

__device__ __forceinline__ float wave_sum(float x) {
    #pragma unroll
    for (int o = 32; o > 0; o >>= 1) x += __shfl_down(x, o, 64);
    return x;
}

// Fused finalize: blocks [0,32) per-pred reduce+terms; [32,80) col-part reduce;
// last block (atomic ticket) computes the final scalar and writes d_out.
#define FIN_PRED_BLOCKS 32
#define FIN_COL_BLOCKS 48      // 48*256 = 12288
#define FIN_TOTAL (FIN_PRED_BLOCKS + FIN_COL_BLOCKS)
__global__ __launch_bounds__(256) void finalize_kernel(const float* __restrict__ pred,
                                                       const float* __restrict__ relpos,
                                                       const int* __restrict__ label,
                                                       const unsigned long long* __restrict__ rowpart,
                                                       const float* __restrict__ colpart,
                                                       const float* __restrict__ pnn,
                                                       const float* __restrict__ gtn,
                                                       const float* __restrict__ nsum,
                                                       const float* __restrict__ deg,
                                                       float* __restrict__ scal,
                                                       unsigned* __restrict__ ticket,
                                                       float* __restrict__ out) {
    if (blockIdx.x < FIN_PRED_BLOCKS) {
        int v = blockIdx.x * 256 + threadIdx.x;
        // reduce 128 chunk partials: u64 min == (min d2, tie -> lowest idx = first occurrence)
        unsigned long long key = 0xFFFFFFFFFFFFFFFFULL;
        #pragma unroll 4
        for (int c = 0; c < ROW_CHUNKS; ++c) {
            unsigned long long k2 = rowpart[(size_t)c * NP + v];
            key = (k2 < key) ? k2 : key;
        }
        float dmin = __uint_as_float((unsigned)(key >> 32));
        int nearest = (int)(unsigned)(key & 0xffffffffu);
        float px = pred[3*v], py = pred[3*v+1], pz = pred[3*v+2];

        // normal consistency (normalize both accumulators on the fly)
        float ax = pnn[3*v], ay = pnn[3*v+1], az = pnn[3*v+2];
        float an = fmaxf(sqrtf(ax*ax + ay*ay + az*az), EPSF);
        float gx = gtn[3*nearest], gy = gtn[3*nearest+1], gz = gtn[3*nearest+2];
        float gn = fmaxf(sqrtf(gx*gx + gy*gy + gz*gz), EPSF);
        float nx = ax/an - gx/gn, ny = ay/an - gy/gn, nz = az/an - gz/gn;
        float sse = nx*nx + ny*ny + nz*nz;

        // laplacian
        float d = fmaxf(deg[v], 1.0f);
        float lx = nsum[3*v]/d - px, ly = nsum[3*v+1]/d - py, lz = nsum[3*v+2]/d - pz;
        float lapn = sqrtf(lx*lx + ly*ly + lz*lz);

        // grid-sample target (nearest, align_corners=True, zeros padding)
        int ix = (int)rintf(px * 95.0f), iy = (int)rintf(py * 95.0f), iz = (int)rintf(pz * 95.0f);
        bool inb = (ix >= 0) & (ix < 96) & (iy >= 0) & (iy < 96) & (iz >= 0) & (iz < 96);
        int ixc = min(max(ix, 0), 95), iyc = min(max(iy, 0), 95), izc = min(max(iz, 0), 95);
        bool pos = inb && (label[(izc*96 + iyc)*96 + ixc] == 1);

        float p = fminf(fmaxf(relpos[v], EPSF), 1.0f - EPSF);
        float om = 1.0f - p;
        float pcnt = 0.0f, sx = 0.0f, sy = 0.0f;
        if (pos) { pcnt = 1.0f; sx = om*om*logf(p); }
        else     { sy = p*p*logf(om); }

        float r0 = wave_sum(dmin);
        float r1 = wave_sum(sse);
        float r2 = wave_sum(lapn);
        float r3 = wave_sum(pcnt);
        float r4 = wave_sum(sx);
        float r5 = wave_sum(sy);
        if ((threadIdx.x & 63) == 0) {
            atomicAdd(&scal[0], r0);
            atomicAdd(&scal[5], r1);
            atomicAdd(&scal[6], r2);
            atomicAdd(&scal[2], r3);
            atomicAdd(&scal[3], r4);
            atomicAdd(&scal[4], r5);
        }
    } else {
        int gv = (blockIdx.x - FIN_PRED_BLOCKS) * 256 + threadIdx.x;
        float best = 3.4e38f;
        #pragma unroll 4
        for (int c = 0; c < COL_CHUNKS; ++c)
            best = fminf(best, colpart[(size_t)c * NGPAD + gv]);
        float val = (gv < NG) ? best : 0.0f;
        float r = wave_sum(val);
        if ((threadIdx.x & 63) == 0) atomicAdd(&scal[1], r);
    }

    // last-block combine (device-scope atomics; fence orders our adds before ticket)
    __threadfence();
    __shared__ int is_last;
    if (threadIdx.x == 0) {
        unsigned t = atomicAdd(ticket, 1u);
        is_last = (t == FIN_TOTAL - 1) ? 1 : 0;
    }
    __syncthreads();
    if (is_last && threadIdx.x == 0) {
        float sum_row = atomicAdd(&scal[0], 0.0f);
        float sum_col = atomicAdd(&scal[1], 0.0f);
        float pc      = atomicAdd(&scal[2], 0.0f);
        float SX      = atomicAdd(&scal[3], 0.0f);
        float SY      = atomicAdd(&scal[4], 0.0f);
        float sse     = atomicAdd(&scal[5], 0.0f);
        float lap     = atomicAdd(&scal[6], 0.0f);
        float tot = (float)NP;
        float alpha = (tot - pc) / (tot + EPSF);
        float spatial = (-alpha * SX - (1.0f - alpha) * SY) / (tot + EPSF);
        float distance = sum_row / (float)NP + sum_col / (float)NG;
        float normal = sse / (float)(NP * 3);
        float lapm = lap / (float)NP;
        out[0] = spatial + 1.0f * distance + 0.01f * normal + 0.1f * lapm;
    }
}

extern "C" void kernel_launch(void* const* d_in, const int* in_sizes, int n_in,
                              void* d_out, int out_size, void* d_ws, size_t ws_size,
                              hipStream_t stream) {
    const float* pred   = (const float*)d_in[0];   // [8192,3]
    const float* relpos = (const float*)d_in[1];   // [8192]
    const float* gt     = (const float*)d_in[2];   // [12000,3]
    const int*   pfaces = (const int*)d_in[3];     // [16384,3]
    const int*   gfaces = (const int*)d_in[4];     // [24000,3]
    const int*   label  = (const int*)d_in[5];     // [1,1,96,96,96]
    float* out = (float*)d_out;

    char* ws = (char*)d_ws;
    unsigned long long* rowpart = (unsigned long long*)(ws + OFF_ROWPART);
    float*              colpart = (float*)(ws + OFF_COLPART);
    float*              gtn     = (float*)(ws + OFF_GTN);
    float*              pnn     = (float*)(ws + OFF_PNN);
    float*              nsum    = (float*)(ws + OFF_NSUM);
    float*              deg     = (float*)(ws + OFF_DEG);
    float*              scal    = (float*)(ws + OFF_SCAL);
    unsigned*           ticket  = (unsigned*)(ws + OFF_SCAL + 7*sizeof(float));

    hipLaunchKernelGGL(init_kernel, dim3((N_ZERO + 255) / 256), dim3(256), 0, stream,
                       gtn);
    hipLaunchKernelGGL(mega_kernel, dim3(CD_BLOCKS + FACE_BLOCKS), dim3(256), 0, stream,
                       pred, pfaces, gt, gfaces, rowpart, colpart, gtn, pnn, nsum, deg);
    hipLaunchKernelGGL(finalize_kernel, dim3(FIN_TOTAL), dim3(256), 0, stream,
                       pred, relpos, label, rowpart, colpart, pnn, gtn, nsum, deg,
                       scal, ticket, out);
}